// Round 9
// baseline (465.462 us; speedup 1.0000x reference)
//
#include <hip/hip_runtime.h>

#define EPS 1e-5f

constexpr int Bb  = 128;     // batches
constexpr int Np  = 8192;    // points per batch
constexpr int C1  = 64, C2 = 128, C3 = 256;
constexpr int P   = 64;      // points per chunk (16 rows per wave x 4 waves)
constexpr int CHUNKS = 8;    // chunks per block
constexpr int PTS_PER_BLOCK = P * CHUNKS;          // 512
constexpr int BLK_PER_BATCH = Np / PTS_PER_BLOCK;  // 16

typedef __attribute__((ext_vector_type(8))) short short8v;  // 8 bf16 = 4 VGPR
typedef __attribute__((ext_vector_type(4))) float f32x4;    // MFMA acc

__device__ __forceinline__ ushort f2bf(float f) {
  uint x = __float_as_uint(f);
  return (ushort)((x + 0x7fffu + ((x >> 16) & 1u)) >> 16);   // RNE
}

__device__ __forceinline__ uint cvt_pk_bf16(float lo, float hi) {
  uint r;
  asm("v_cvt_pk_bf16_f32 %0, %1, %2" : "=v"(r) : "v"(lo), "v"(hi));
  return r;
}

// ---------------------------------------------------------------------------
// prepW: pack W2 [64][128] and W3 [128][256] (f32) into bf16 B-fragments for
// v_mfma_f32_16x16x32_bf16.  Frag order: [tile][kk][lane][i] with
// k = kk*32 + (lane>>4)*8 + i,  n = tile*16 + (lane&15).
// ---------------------------------------------------------------------------
__global__ __launch_bounds__(256) void prepW(const float* __restrict__ W2,
                                             const float* __restrict__ W3,
                                             ushort* __restrict__ W2s,
                                             ushort* __restrict__ W3s) {
  const int idx = blockIdx.x * 256 + threadIdx.x;   // 0..40959
  if (idx < 8192) {
    const int i  = idx & 7;
    const int l  = (idx >> 3) & 63;
    const int kk = (idx >> 9) & 1;
    const int t  = idx >> 10;
    const int k  = kk * 32 + (l >> 4) * 8 + i;
    const int n  = t * 16 + (l & 15);
    W2s[idx] = f2bf(W2[k * C2 + n]);
  } else {
    const int j  = idx - 8192;                      // 0..32767
    const int i  = j & 7;
    const int l  = (j >> 3) & 63;
    const int kk = (j >> 9) & 3;
    const int nt = j >> 11;
    const int k  = kk * 32 + (l >> 4) * 8 + i;
    const int n  = nt * 16 + (l & 15);
    W3s[j] = f2bf(W3[k * C3 + n]);
  }
}

// ---------------------------------------------------------------------------
// Stage A — zero-barrier chunk loop at 256 threads (r7 dataflow, r8 lessons):
//  * Wave owns 16 rows x FULL N for all 3 layers: LN1/LN2/LN3 all in-wave
//    shuffle reductions; h1/h2 wave-private LDS; NO barrier in chunk loop.
//  * L3 SINGLE pass: acc3[16] (64 VGPR) held only through its own LN.
//    256-thr blocks: allocator grants >128 VGPR without hints (r6: 184).
//    (r7's 512-thr version was capped at 128 and spilled 3.3 GB.)
//  * W3 (64KB) + W2 (16KB) frags + all params (6KB) staged in LDS once.
//    LDS 110KB -> 1 block/CU BY DESIGN: 4 independent barrier-free waves,
//    in-wave ILP (16 indep MFMA chains) hides latency instead of TLP.
//  * Bias folded into MFMA C-init; v_cvt_pk_bf16_f32 for f32->bf16 pairs.
// s_par layout (floats): W1[3][64]@0, b1@192, g1@256, be1@320, b2@384,
//                        g2@512, be2@640, b3@768, g3@1024, be3@1280.
// ---------------------------------------------------------------------------
__global__ __launch_bounds__(256) void stageA(
    const float* __restrict__ pc,
    const float* __restrict__ W1, const float* __restrict__ b1,
    const float* __restrict__ g1, const float* __restrict__ be1,
    const ushort* __restrict__ W2s, const float* __restrict__ b2,
    const float* __restrict__ g2, const float* __restrict__ be2,
    const ushort* __restrict__ W3s, const float* __restrict__ b3,
    const float* __restrict__ g3, const float* __restrict__ be3,
    float* __restrict__ pooled)      // [B][C3], pre-zeroed, int-bits atomicMax
{
  __shared__ __align__(16) ushort s_w3[32768];         // 64KB W3 frags
  __shared__ __align__(16) ushort s_w2[8192];          // 16KB W2 frags
  __shared__ __align__(16) ushort s_h1[4 * 1024];      // 8KB per-wave [16][64]
  __shared__ __align__(16) ushort s_h2[4 * 2048];      // 16KB per-wave [16][128]
  __shared__ float s_par[1536];                        // 6KB params

  const int tid  = threadIdx.x;
  const int lane = tid & 63;
  const int w    = tid >> 6;
  const int lrow = lane & 15;            // A-row / C-D col index
  const int lgrp = lane >> 4;
  const int b    = blockIdx.x >> 4;      // / BLK_PER_BATCH
  const int base_pt = (blockIdx.x & (BLK_PER_BATCH - 1)) * PTS_PER_BLOCK;

  // ---- one-time staging ----
  for (int i = tid; i < 1536; i += 256) {
    float v;
    if      (i <  192) v = W1 [i];
    else if (i <  256) v = b1 [i - 192];
    else if (i <  320) v = g1 [i - 256];
    else if (i <  384) v = be1[i - 320];
    else if (i <  512) v = b2 [i - 384];
    else if (i <  640) v = g2 [i - 512];
    else if (i <  768) v = be2[i - 640];
    else if (i < 1024) v = b3 [i - 768];
    else if (i < 1280) v = g3 [i - 1024];
    else               v = be3[i - 1280];
    s_par[i] = v;
  }
#pragma unroll
  for (int q = 0; q < 4; ++q)
    ((uint4*)s_w2)[q * 256 + tid] = ((const uint4*)W2s)[q * 256 + tid];
#pragma unroll
  for (int q = 0; q < 16; ++q)
    ((uint4*)s_w3)[q * 256 + tid] = ((const uint4*)W3s)[q * 256 + tid];
  __syncthreads();   // the ONLY barrier

  char* const h1b = (char*)(s_h1 + w * 1024);   // wave-private 16x64 bf16
  char* const h2b = (char*)(s_h2 + w * 2048);   // wave-private 16x128 bf16
  const int sw1 = (lrow & 7) << 4;

  float runmax[16];
#pragma unroll
  for (int t = 0; t < 16; ++t) runmax[t] = 0.f;

  // ---- prefetch chunk 0's point ----
  const float* xp0 = pc + (size_t)(b * Np + base_pt + w * 16 + lrow) * 3;
  float x0 = xp0[0], x1 = xp0[1], x2 = xp0[2];

  for (int ch = 0; ch < CHUNKS; ++ch) {
    // ================= layer 1: 3 -> 64, fp32 VALU =================
    float y[16];
#pragma unroll
    for (int j = 0; j < 16; ++j) {
      const int c = lgrp * 16 + j;
      y[j] = x0 * s_par[c] + x1 * s_par[64 + c] + x2 * s_par[128 + c] + s_par[192 + c];
    }
    // issue next chunk's pc load now (consumed next iteration)
    {
      const int chn = (ch + 1 < CHUNKS) ? ch + 1 : ch;
      const float* xpn = pc + (size_t)(b * Np + base_pt + chn * P + w * 16 + lrow) * 3;
      x0 = xpn[0]; x1 = xpn[1]; x2 = xpn[2];
    }
    float s1 = 0.f, q1 = 0.f;
#pragma unroll
    for (int j = 0; j < 16; ++j) { s1 += y[j]; q1 += y[j] * y[j]; }
    s1 += __shfl_xor(s1, 16, 64); q1 += __shfl_xor(q1, 16, 64);
    s1 += __shfl_xor(s1, 32, 64); q1 += __shfl_xor(q1, 32, 64);
    const float m1 = s1 * (1.f / 64.f);
    const float i1 = rsqrtf(q1 * (1.f / 64.f) - m1 * m1 + EPS);
    {
      uint pk[8];
#pragma unroll
      for (int j2 = 0; j2 < 8; ++j2) {
        const int c0 = lgrp * 16 + 2 * j2;
        const float h0 = fmaxf((y[2 * j2]     - m1) * i1 * s_par[256 + c0]     + s_par[320 + c0],     0.f);
        const float h1 = fmaxf((y[2 * j2 + 1] - m1) * i1 * s_par[256 + c0 + 1] + s_par[320 + c0 + 1], 0.f);
        pk[j2] = cvt_pk_bf16(h0, h1);
      }
      const int base = lrow * 128 + lgrp * 32;   // bytes
      *(uint4*)(h1b + ((base     ) ^ sw1)) = make_uint4(pk[0], pk[1], pk[2], pk[3]);
      *(uint4*)(h1b + ((base + 16) ^ sw1)) = make_uint4(pk[4], pk[5], pk[6], pk[7]);
    }
    // wave-private region: compiler lgkmcnt orders write->read; no barrier.

    // ================= layer 2: 64 -> 128, MFMA (in-wave) =================
    short8v a2[2];
#pragma unroll
    for (int kk = 0; kk < 2; ++kk)
      a2[kk] = *(const short8v*)(h1b + ((lrow * 128 + (kk * 64 + lgrp * 16)) ^ sw1));
    {
      f32x4 acc2[8];
      float s2[4] = {0.f,0.f,0.f,0.f}, q2[4] = {0.f,0.f,0.f,0.f};
#pragma unroll
      for (int t = 0; t < 8; ++t) {
        const float bb = s_par[384 + t * 16 + lrow];
        acc2[t] = (f32x4){bb, bb, bb, bb};         // bias as C-init
#pragma unroll
        for (int kk = 0; kk < 2; ++kk) {
          const short8v w2f = *(const short8v*)((const char*)s_w2 + (((t * 2 + kk) << 6) + lane) * 16);
          acc2[t] = __builtin_amdgcn_mfma_f32_16x16x32_bf16(a2[kk], w2f, acc2[t], 0, 0, 0);
        }
#pragma unroll
        for (int j = 0; j < 4; ++j) {
          const float v = acc2[t][j];
          s2[j] += v; q2[j] += v * v;
        }
      }
#pragma unroll
      for (int m = 1; m < 16; m <<= 1)
#pragma unroll
        for (int j = 0; j < 4; ++j) {
          s2[j] += __shfl_xor(s2[j], m, 64);
          q2[j] += __shfl_xor(q2[j], m, 64);
        }
#pragma unroll
      for (int j = 0; j < 4; ++j) {
        const float m2 = s2[j] * (1.f / 128.f);
        const float i2 = rsqrtf(q2[j] * (1.f / 128.f) - m2 * m2 + EPS);
        const int row = lgrp * 4 + j;              // wave-local row
        const int swr = (row & 7) << 4;
        const int rowb = row * 256;
#pragma unroll
        for (int t2 = 0; t2 < 4; ++t2) {           // pairs (2t2, 2t2+1)
          const int ca = t2 * 32 + lrow, cb = ca + 16;
          const float ha = fmaxf((acc2[2*t2  ][j] - m2) * i2 * s_par[512 + ca] + s_par[640 + ca], 0.f);
          const float hb = fmaxf((acc2[2*t2+1][j] - m2) * i2 * s_par[512 + cb] + s_par[640 + cb], 0.f);
          const uint pkv = cvt_pk_bf16(ha, hb);
          *(ushort*)(h2b + rowb + ((t2 * 64      + lrow * 2) ^ swr)) = (ushort)pkv;
          *(ushort*)(h2b + rowb + ((t2 * 64 + 32 + lrow * 2) ^ swr)) = (ushort)(pkv >> 16);
        }
      }
    }

    // ======== layer 3: 128 -> 256, MFMA, single pass, in-wave LN ==========
    short8v a3[4];
#pragma unroll
    for (int kk = 0; kk < 4; ++kk)
      a3[kk] = *(const short8v*)(h2b + (lrow * 256 + ((kk * 64 + lgrp * 16) ^ ((lrow & 7) << 4))));

    f32x4 acc3[16];
    float sj[4] = {0.f,0.f,0.f,0.f}, qj[4] = {0.f,0.f,0.f,0.f};
#pragma unroll
    for (int t = 0; t < 16; ++t) {
      const float bb = s_par[768 + t * 16 + lrow];
      acc3[t] = (f32x4){bb, bb, bb, bb};           // bias as C-init
#pragma unroll
      for (int kk = 0; kk < 4; ++kk) {
        const short8v w3f = *(const short8v*)((const char*)s_w3 + (((t * 4 + kk) << 6) + lane) * 16);
        acc3[t] = __builtin_amdgcn_mfma_f32_16x16x32_bf16(a3[kk], w3f, acc3[t], 0, 0, 0);
      }
#pragma unroll
      for (int j = 0; j < 4; ++j) {
        const float v = acc3[t][j];
        sj[j] += v; qj[j] += v * v;
      }
    }
#pragma unroll
    for (int m = 1; m < 16; m <<= 1)
#pragma unroll
      for (int j = 0; j < 4; ++j) {
        sj[j] += __shfl_xor(sj[j], m, 64);
        qj[j] += __shfl_xor(qj[j], m, 64);
      }
    float mean3[4], inv3[4];
#pragma unroll
    for (int j = 0; j < 4; ++j) {
      mean3[j] = sj[j] * (1.f / 256.f);
      inv3[j]  = rsqrtf(qj[j] * (1.f / 256.f) - mean3[j] * mean3[j] + EPS);
    }
#pragma unroll
    for (int t = 0; t < 16; ++t) {
      const int col = t * 16 + lrow;
      const float gg = s_par[1024 + col], ee = s_par[1280 + col];
      float mx = runmax[t];
#pragma unroll
      for (int j = 0; j < 4; ++j) {
        const float h = fmaxf((acc3[t][j] - mean3[j]) * inv3[j] * gg + ee, 0.f);
        mx = fmaxf(mx, h);
      }
      runmax[t] = mx;
    }
  }

  // ---- col max across the 4 lgrp groups, then global atomic ----
#pragma unroll
  for (int t = 0; t < 16; ++t) {
    float v = runmax[t];
    v = fmaxf(v, __shfl_xor(v, 16, 64));
    v = fmaxf(v, __shfl_xor(v, 32, 64));
    if (lane < 16)
      atomicMax((int*)&pooled[b * C3 + t * 16 + lane], __float_as_int(v));
  }
}

// ---------------------------------------------------------------------------
// Stage B: pooled -> LN(pooled@Wp+bp) -> film = pc@Wf+bf -> out = s*img + b
// 4 blocks per batch (redundant tiny Wp/LN); each does 1/4 of the Wf columns.
// ---------------------------------------------------------------------------
__global__ __launch_bounds__(256) void stageB(
    const float* __restrict__ pooled,  // [B][256]
    const float* __restrict__ img,     // [B][512]
    const float* __restrict__ Wp, const float* __restrict__ bp,
    const float* __restrict__ gp, const float* __restrict__ bep,
    const float* __restrict__ Wf, const float* __restrict__ bf,
    float* __restrict__ out)           // [B][512]
{
  __shared__ float s_pool[C3];
  __shared__ float s_pc[C3];
  __shared__ float s_red[8];
  __shared__ float s_film[256];

  const int t = threadIdx.x;
  const int b = blockIdx.x >> 2;
  const int qq = blockIdx.x & 3;
  const int lane = t & 63, w = t >> 6;

  s_pool[t] = pooled[b * C3 + t];
  __syncthreads();

  float ya = bp[t], yb = 0.f;
  for (int k = 0; k < C3; k += 2) {
    ya += s_pool[k]     * Wp[k * C3 + t];
    yb += s_pool[k + 1] * Wp[(k + 1) * C3 + t];
  }
  const float y = ya + yb;

  float s = y, q = y * y;
  for (int m = 1; m < 64; m <<= 1) { s += __shfl_xor(s, m, 64); q += __shfl_xor(q, m, 64); }
  if (lane == 0) { s_red[w * 2] = s; s_red[w * 2 + 1] = q; }
  __syncthreads();
  s = s_red[0] + s_red[2] + s_red[4] + s_red[6];
  q = s_red[1] + s_red[3] + s_red[5] + s_red[7];
  const float mean = s * (1.f / 256.f);
  const float var  = q * (1.f / 256.f) - mean * mean;
  const float inv  = rsqrtf(var + EPS);
  s_pc[t] = (y - mean) * inv * gp[t] + bep[t];
  __syncthreads();

  // this block's film column: t<128 -> scale col qq*128+t; t>=128 -> bias col
  const int cc = qq * 128 + (t & 127) + ((t >> 7) * 512);
  float fa = bf[cc], fb = 0.f;
  for (int k = 0; k < C3; k += 2) {
    fa += s_pc[k]     * Wf[k * 1024 + cc];
    fb += s_pc[k + 1] * Wf[(k + 1) * 1024 + cc];
  }
  s_film[t] = fa + fb;
  __syncthreads();

  if (t < 128) {
    const int col = qq * 128 + t;
    out[b * 512 + col] = s_film[t] * img[b * 512 + col] + s_film[128 + t];
  }
}

extern "C" void kernel_launch(void* const* d_in, const int* in_sizes, int n_in,
                              void* d_out, int out_size, void* d_ws, size_t ws_size,
                              hipStream_t stream) {
  const float* pc  = (const float*)d_in[0];
  const float* img = (const float*)d_in[1];
  const float* W1  = (const float*)d_in[2];
  const float* b1  = (const float*)d_in[3];
  const float* g1  = (const float*)d_in[4];
  const float* be1 = (const float*)d_in[5];
  const float* W2  = (const float*)d_in[6];
  const float* b2  = (const float*)d_in[7];
  const float* g2  = (const float*)d_in[8];
  const float* be2 = (const float*)d_in[9];
  const float* W3  = (const float*)d_in[10];
  const float* b3  = (const float*)d_in[11];
  const float* g3  = (const float*)d_in[12];
  const float* be3 = (const float*)d_in[13];
  const float* Wp  = (const float*)d_in[14];
  const float* bp  = (const float*)d_in[15];
  const float* gp  = (const float*)d_in[16];
  const float* bep = (const float*)d_in[17];
  const float* Wf  = (const float*)d_in[18];
  const float* bf  = (const float*)d_in[19];

  float*  pooled = (float*)d_ws;                                   // 128 KB
  ushort* W2s = (ushort*)((char*)d_ws + Bb * C3 * sizeof(float));  // 16 KB
  ushort* W3s = W2s + 8192;                                        // 64 KB

  hipMemsetAsync(pooled, 0, Bb * C3 * sizeof(float), stream);
  prepW<<<160, 256, 0, stream>>>(W2, W3, W2s, W3s);
  stageA<<<Bb * BLK_PER_BATCH, 256, 0, stream>>>(
      pc, W1, b1, g1, be1, W2s, b2, g2, be2, W3s, b3, g3, be3, pooled);
  stageB<<<Bb * 4, 256, 0, stream>>>(pooled, img, Wp, bp, gp, bep, Wf, bf,
                                     (float*)d_out);
}

// Round 10
// 360.113 us; speedup vs baseline: 1.2925x; 1.2925x over previous
//
#include <hip/hip_runtime.h>

#define EPS 1e-5f

constexpr int Bb  = 128;     // batches
constexpr int Np  = 8192;    // points per batch
constexpr int C1  = 64, C2 = 128, C3 = 256;
constexpr int WAVES = 8;     // 512 threads
constexpr int P   = 128;     // points per chunk = 8 waves x 16 rows
constexpr int CHUNKS = 8;
constexpr int PTS_PER_BLOCK = P * CHUNKS;          // 1024
constexpr int BLK_PER_BATCH = Np / PTS_PER_BLOCK;  // 8

typedef __attribute__((ext_vector_type(8))) short short8v;  // 8 bf16 = 4 VGPR
typedef __attribute__((ext_vector_type(4))) float f32x4;    // MFMA acc

__device__ __forceinline__ ushort f2bf(float f) {
  uint x = __float_as_uint(f);
  return (ushort)((x + 0x7fffu + ((x >> 16) & 1u)) >> 16);   // RNE
}

__device__ __forceinline__ uint cvt_pk_bf16(float lo, float hi) {
  uint r;
  asm("v_cvt_pk_bf16_f32 %0, %1, %2" : "=v"(r) : "v"(lo), "v"(hi));
  return r;
}

// ---------------------------------------------------------------------------
// prepW: pack W2 [64][128] and W3 [128][256] (f32) into bf16 B-fragments.
// W2 frag k-order: identity  k = kk*32 + (l>>4)*8 + i   (matches h1 layout).
// W3 frag k-order: PERMUTED  s=(l>>4)*8+i, k = kk*32 + (s>>1) + 16*(s&1)
//   — matches h2's pair-interleaved slot layout (uint pair writes in LN2).
//   Any k-bijection shared by A(h2) and B(W3) is legal.
// ---------------------------------------------------------------------------
__global__ __launch_bounds__(256) void prepW(const float* __restrict__ W2,
                                             const float* __restrict__ W3,
                                             ushort* __restrict__ W2s,
                                             ushort* __restrict__ W3s) {
  const int idx = blockIdx.x * 256 + threadIdx.x;   // 0..40959
  if (idx < 8192) {
    const int i  = idx & 7;
    const int l  = (idx >> 3) & 63;
    const int kk = (idx >> 9) & 1;
    const int t  = idx >> 10;
    const int k  = kk * 32 + (l >> 4) * 8 + i;
    const int n  = t * 16 + (l & 15);
    W2s[idx] = f2bf(W2[k * C2 + n]);
  } else {
    const int j  = idx - 8192;                      // 0..32767
    const int i  = j & 7;
    const int l  = (j >> 3) & 63;
    const int kk = (j >> 9) & 3;
    const int nt = j >> 11;
    const int s  = (l >> 4) * 8 + i;
    const int k  = kk * 32 + (s >> 1) + 16 * (s & 1);   // pair-interleaved
    const int n  = nt * 16 + (l & 15);
    W3s[j] = f2bf(W3[k * C3 + n]);
  }
}

// ---------------------------------------------------------------------------
// Stage A — zero-barrier chunk loop at 512 threads (8 waves = 2/SIMD):
//  * r9 dataflow (wave owns 16 rows x full N; all LNs in-wave; wave-private
//    h1/h2; no barrier in the chunk loop) + r9's 1-wave/SIMD fix: 134KB LDS
//    at 512 thr -> 1 block/CU -> 2 waves/SIMD for stall overlap.
//  * Designed for the 128-VGPR cap hipcc pins at 512-thr blocks (r7 lesson):
//    L3 computed in two 8-tile halves; half A re-packed to bf16 (16 regs)
//    before half B is computed. LN stats stay exact f32. Peak ~110 VGPR.
//  * h2 pair writes as single uint (pair-interleaved k-slots; W3 prep uses
//    the same permutation).
// s_par layout (floats): W1[3][64]@0, b1@192, g1@256, be1@320, b2@384,
//                        g2@512, be2@640, b3@768, g3@1024, be3@1280.
// ---------------------------------------------------------------------------
__global__ __launch_bounds__(512) void stageA(
    const float* __restrict__ pc,
    const float* __restrict__ W1, const float* __restrict__ b1,
    const float* __restrict__ g1, const float* __restrict__ be1,
    const ushort* __restrict__ W2s, const float* __restrict__ b2,
    const float* __restrict__ g2, const float* __restrict__ be2,
    const ushort* __restrict__ W3s, const float* __restrict__ b3,
    const float* __restrict__ g3, const float* __restrict__ be3,
    float* __restrict__ pooled)      // [B][C3], pre-zeroed, int-bits atomicMax
{
  __shared__ __align__(16) ushort s_w3[32768];           // 64KB W3 frags
  __shared__ __align__(16) ushort s_w2[8192];            // 16KB W2 frags
  __shared__ __align__(16) ushort s_h1[WAVES * 1024];    // 16KB per-wave 16x64
  __shared__ __align__(16) ushort s_h2[WAVES * 2048];    // 32KB per-wave 16x128
  __shared__ float s_par[1536];                          // 6KB params

  const int tid  = threadIdx.x;          // 0..511
  const int lane = tid & 63;
  const int w    = tid >> 6;
  const int lrow = lane & 15;            // A-row / C-D col index
  const int lgrp = lane >> 4;
  const int b    = blockIdx.x >> 3;      // / BLK_PER_BATCH
  const int base_pt = (blockIdx.x & (BLK_PER_BATCH - 1)) * PTS_PER_BLOCK;

  // ---- one-time staging ----
  for (int i = tid; i < 1536; i += 512) {
    float v;
    if      (i <  192) v = W1 [i];
    else if (i <  256) v = b1 [i - 192];
    else if (i <  320) v = g1 [i - 256];
    else if (i <  384) v = be1[i - 320];
    else if (i <  512) v = b2 [i - 384];
    else if (i <  640) v = g2 [i - 512];
    else if (i <  768) v = be2[i - 640];
    else if (i < 1024) v = b3 [i - 768];
    else if (i < 1280) v = g3 [i - 1024];
    else               v = be3[i - 1280];
    s_par[i] = v;
  }
#pragma unroll
  for (int q = 0; q < 2; ++q)
    ((uint4*)s_w2)[q * 512 + tid] = ((const uint4*)W2s)[q * 512 + tid];
#pragma unroll
  for (int q = 0; q < 8; ++q)
    ((uint4*)s_w3)[q * 512 + tid] = ((const uint4*)W3s)[q * 512 + tid];
  __syncthreads();   // the ONLY barrier

  char* const h1b = (char*)(s_h1 + w * 1024);   // wave-private 16x64 bf16
  char* const h2b = (char*)(s_h2 + w * 2048);   // wave-private 16x128 bf16
  const int sw1 = (lrow & 7) << 4;

  float runmax[16];
#pragma unroll
  for (int t = 0; t < 16; ++t) runmax[t] = 0.f;

  // ---- prefetch chunk 0's point ----
  const float* xp0 = pc + (size_t)(b * Np + base_pt + w * 16 + lrow) * 3;
  float x0 = xp0[0], x1 = xp0[1], x2 = xp0[2];

  for (int ch = 0; ch < CHUNKS; ++ch) {
    // ================= layer 1: 3 -> 64, fp32 VALU =================
    float y[16];
#pragma unroll
    for (int j = 0; j < 16; ++j) {
      const int c = lgrp * 16 + j;
      y[j] = x0 * s_par[c] + x1 * s_par[64 + c] + x2 * s_par[128 + c] + s_par[192 + c];
    }
    {  // issue next chunk's pc load now
      const int chn = (ch + 1 < CHUNKS) ? ch + 1 : ch;
      const float* xpn = pc + (size_t)(b * Np + base_pt + chn * P + w * 16 + lrow) * 3;
      x0 = xpn[0]; x1 = xpn[1]; x2 = xpn[2];
    }
    float s1 = 0.f, q1 = 0.f;
#pragma unroll
    for (int j = 0; j < 16; ++j) { s1 += y[j]; q1 += y[j] * y[j]; }
    s1 += __shfl_xor(s1, 16, 64); q1 += __shfl_xor(q1, 16, 64);
    s1 += __shfl_xor(s1, 32, 64); q1 += __shfl_xor(q1, 32, 64);
    const float m1 = s1 * (1.f / 64.f);
    const float i1 = rsqrtf(q1 * (1.f / 64.f) - m1 * m1 + EPS);
    {
      uint pk[8];
#pragma unroll
      for (int j2 = 0; j2 < 8; ++j2) {
        const int c0 = lgrp * 16 + 2 * j2;
        const float h0 = fmaxf((y[2 * j2]     - m1) * i1 * s_par[256 + c0]     + s_par[320 + c0],     0.f);
        const float h1 = fmaxf((y[2 * j2 + 1] - m1) * i1 * s_par[256 + c0 + 1] + s_par[320 + c0 + 1], 0.f);
        pk[j2] = cvt_pk_bf16(h0, h1);
      }
      const int base = lrow * 128 + lgrp * 32;   // bytes
      *(uint4*)(h1b + ((base     ) ^ sw1)) = make_uint4(pk[0], pk[1], pk[2], pk[3]);
      *(uint4*)(h1b + ((base + 16) ^ sw1)) = make_uint4(pk[4], pk[5], pk[6], pk[7]);
    }
    // wave-private region: compiler lgkmcnt orders write->read; no barrier.

    // ================= layer 2: 64 -> 128, MFMA (in-wave) =================
    short8v a2[2];
#pragma unroll
    for (int kk = 0; kk < 2; ++kk)
      a2[kk] = *(const short8v*)(h1b + ((lrow * 128 + (kk * 64 + lgrp * 16)) ^ sw1));
    {
      f32x4 acc2[8];
      float s2[4] = {0.f,0.f,0.f,0.f}, q2[4] = {0.f,0.f,0.f,0.f};
#pragma unroll
      for (int t = 0; t < 8; ++t) {
        const float bb = s_par[384 + t * 16 + lrow];
        acc2[t] = (f32x4){bb, bb, bb, bb};         // bias as C-init
#pragma unroll
        for (int kk = 0; kk < 2; ++kk) {
          const short8v w2f = *(const short8v*)((const char*)s_w2 + (((t * 2 + kk) << 6) + lane) * 16);
          acc2[t] = __builtin_amdgcn_mfma_f32_16x16x32_bf16(a2[kk], w2f, acc2[t], 0, 0, 0);
        }
#pragma unroll
        for (int j = 0; j < 4; ++j) {
          const float v = acc2[t][j];
          s2[j] += v; q2[j] += v * v;
        }
      }
#pragma unroll
      for (int m = 1; m < 16; m <<= 1)
#pragma unroll
        for (int j = 0; j < 4; ++j) {
          s2[j] += __shfl_xor(s2[j], m, 64);
          q2[j] += __shfl_xor(q2[j], m, 64);
        }
#pragma unroll
      for (int j = 0; j < 4; ++j) {
        const float m2 = s2[j] * (1.f / 128.f);
        const float i2 = rsqrtf(q2[j] * (1.f / 128.f) - m2 * m2 + EPS);
        const int row = lgrp * 4 + j;              // wave-local row
        const int swr = (row & 7) << 4;
        const int rowb = row * 256;
#pragma unroll
        for (int t2 = 0; t2 < 4; ++t2) {           // cols (t2*32+lrow, +16) -> one uint
          const int ca = t2 * 32 + lrow, cb = ca + 16;
          const float ha = fmaxf((acc2[2*t2  ][j] - m2) * i2 * s_par[512 + ca] + s_par[640 + ca], 0.f);
          const float hb = fmaxf((acc2[2*t2+1][j] - m2) * i2 * s_par[512 + cb] + s_par[640 + cb], 0.f);
          *(uint*)(h2b + rowb + ((t2 * 64 + lrow * 4) ^ swr)) = cvt_pk_bf16(ha, hb);
        }
      }
    }

    // ======== layer 3: 128 -> 256, MFMA, two halves, in-wave LN ==========
    short8v a3[4];
#pragma unroll
    for (int kk = 0; kk < 4; ++kk)
      a3[kk] = *(const short8v*)(h2b + (lrow * 256 + ((kk * 64 + lgrp * 16) ^ sw1)));

    float sj[4] = {0.f,0.f,0.f,0.f}, qj[4] = {0.f,0.f,0.f,0.f};
    uint pA[16];                     // half A re-packed to bf16 (frees 32 regs)
    {
      f32x4 accA[8];
#pragma unroll
      for (int t = 0; t < 8; ++t) {
        const float bb = s_par[768 + t * 16 + lrow];
        accA[t] = (f32x4){bb, bb, bb, bb};
#pragma unroll
        for (int kk = 0; kk < 4; ++kk) {
          const short8v w3f = *(const short8v*)((const char*)s_w3 + (((t * 4 + kk) << 6) + lane) * 16);
          accA[t] = __builtin_amdgcn_mfma_f32_16x16x32_bf16(a3[kk], w3f, accA[t], 0, 0, 0);
        }
#pragma unroll
        for (int j = 0; j < 4; ++j) { const float v = accA[t][j]; sj[j] += v; qj[j] += v * v; }
      }
#pragma unroll
      for (int t = 0; t < 8; ++t) {
        pA[2*t]   = cvt_pk_bf16(accA[t][0], accA[t][1]);
        pA[2*t+1] = cvt_pk_bf16(accA[t][2], accA[t][3]);
      }
    }
    f32x4 accB[8];
#pragma unroll
    for (int t = 8; t < 16; ++t) {
      const float bb = s_par[768 + t * 16 + lrow];
      accB[t-8] = (f32x4){bb, bb, bb, bb};
#pragma unroll
      for (int kk = 0; kk < 4; ++kk) {
        const short8v w3f = *(const short8v*)((const char*)s_w3 + (((t * 4 + kk) << 6) + lane) * 16);
        accB[t-8] = __builtin_amdgcn_mfma_f32_16x16x32_bf16(a3[kk], w3f, accB[t-8], 0, 0, 0);
      }
#pragma unroll
      for (int j = 0; j < 4; ++j) { const float v = accB[t-8][j]; sj[j] += v; qj[j] += v * v; }
    }
#pragma unroll
    for (int m = 1; m < 16; m <<= 1)
#pragma unroll
      for (int j = 0; j < 4; ++j) {
        sj[j] += __shfl_xor(sj[j], m, 64);
        qj[j] += __shfl_xor(qj[j], m, 64);
      }
    float mean3[4], inv3[4];
#pragma unroll
    for (int j = 0; j < 4; ++j) {
      mean3[j] = sj[j] * (1.f / 256.f);
      inv3[j]  = rsqrtf(qj[j] * (1.f / 256.f) - mean3[j] * mean3[j] + EPS);
    }
    // normalize half B (exact f32 accs)
#pragma unroll
    for (int t = 8; t < 16; ++t) {
      const int col = t * 16 + lrow;
      const float gg = s_par[1024 + col], ee = s_par[1280 + col];
      float mx = runmax[t];
#pragma unroll
      for (int j = 0; j < 4; ++j)
        mx = fmaxf(mx, fmaxf((accB[t-8][j] - mean3[j]) * inv3[j] * gg + ee, 0.f));
      runmax[t] = mx;
    }
    // normalize half A (bf16-repacked accs)
#pragma unroll
    for (int t = 0; t < 8; ++t) {
      const int col = t * 16 + lrow;
      const float gg = s_par[1024 + col], ee = s_par[1280 + col];
      const float v0 = __uint_as_float(pA[2*t]   << 16);
      const float v1 = __uint_as_float(pA[2*t]   & 0xffff0000u);
      const float v2 = __uint_as_float(pA[2*t+1] << 16);
      const float v3 = __uint_as_float(pA[2*t+1] & 0xffff0000u);
      float mx = runmax[t];
      mx = fmaxf(mx, fmaxf((v0 - mean3[0]) * inv3[0] * gg + ee, 0.f));
      mx = fmaxf(mx, fmaxf((v1 - mean3[1]) * inv3[1] * gg + ee, 0.f));
      mx = fmaxf(mx, fmaxf((v2 - mean3[2]) * inv3[2] * gg + ee, 0.f));
      mx = fmaxf(mx, fmaxf((v3 - mean3[3]) * inv3[3] * gg + ee, 0.f));
      runmax[t] = mx;
    }
  }

  // ---- col max across the 4 lgrp groups, then global atomic ----
#pragma unroll
  for (int t = 0; t < 16; ++t) {
    float v = runmax[t];
    v = fmaxf(v, __shfl_xor(v, 16, 64));
    v = fmaxf(v, __shfl_xor(v, 32, 64));
    if (lane < 16)
      atomicMax((int*)&pooled[b * C3 + t * 16 + lane], __float_as_int(v));
  }
}

// ---------------------------------------------------------------------------
// Stage B: pooled -> LN(pooled@Wp+bp) -> film = pc@Wf+bf -> out = s*img + b
// 4 blocks per batch (redundant tiny Wp/LN); each does 1/4 of the Wf columns.
// ---------------------------------------------------------------------------
__global__ __launch_bounds__(256) void stageB(
    const float* __restrict__ pooled,  // [B][256]
    const float* __restrict__ img,     // [B][512]
    const float* __restrict__ Wp, const float* __restrict__ bp,
    const float* __restrict__ gp, const float* __restrict__ bep,
    const float* __restrict__ Wf, const float* __restrict__ bf,
    float* __restrict__ out)           // [B][512]
{
  __shared__ float s_pool[C3];
  __shared__ float s_pc[C3];
  __shared__ float s_red[8];
  __shared__ float s_film[256];

  const int t = threadIdx.x;
  const int b = blockIdx.x >> 2;
  const int qq = blockIdx.x & 3;
  const int lane = t & 63, w = t >> 6;

  s_pool[t] = pooled[b * C3 + t];
  __syncthreads();

  float ya = bp[t], yb = 0.f;
  for (int k = 0; k < C3; k += 2) {
    ya += s_pool[k]     * Wp[k * C3 + t];
    yb += s_pool[k + 1] * Wp[(k + 1) * C3 + t];
  }
  const float y = ya + yb;

  float s = y, q = y * y;
  for (int m = 1; m < 64; m <<= 1) { s += __shfl_xor(s, m, 64); q += __shfl_xor(q, m, 64); }
  if (lane == 0) { s_red[w * 2] = s; s_red[w * 2 + 1] = q; }
  __syncthreads();
  s = s_red[0] + s_red[2] + s_red[4] + s_red[6];
  q = s_red[1] + s_red[3] + s_red[5] + s_red[7];
  const float mean = s * (1.f / 256.f);
  const float var  = q * (1.f / 256.f) - mean * mean;
  const float inv  = rsqrtf(var + EPS);
  s_pc[t] = (y - mean) * inv * gp[t] + bep[t];
  __syncthreads();

  // this block's film column: t<128 -> scale col qq*128+t; t>=128 -> bias col
  const int cc = qq * 128 + (t & 127) + ((t >> 7) * 512);
  float fa = bf[cc], fb = 0.f;
  for (int k = 0; k < C3; k += 2) {
    fa += s_pc[k]     * Wf[k * 1024 + cc];
    fb += s_pc[k + 1] * Wf[(k + 1) * 1024 + cc];
  }
  s_film[t] = fa + fb;
  __syncthreads();

  if (t < 128) {
    const int col = qq * 128 + t;
    out[b * 512 + col] = s_film[t] * img[b * 512 + col] + s_film[128 + t];
  }
}

extern "C" void kernel_launch(void* const* d_in, const int* in_sizes, int n_in,
                              void* d_out, int out_size, void* d_ws, size_t ws_size,
                              hipStream_t stream) {
  const float* pc  = (const float*)d_in[0];
  const float* img = (const float*)d_in[1];
  const float* W1  = (const float*)d_in[2];
  const float* b1  = (const float*)d_in[3];
  const float* g1  = (const float*)d_in[4];
  const float* be1 = (const float*)d_in[5];
  const float* W2  = (const float*)d_in[6];
  const float* b2  = (const float*)d_in[7];
  const float* g2  = (const float*)d_in[8];
  const float* be2 = (const float*)d_in[9];
  const float* W3  = (const float*)d_in[10];
  const float* b3  = (const float*)d_in[11];
  const float* g3  = (const float*)d_in[12];
  const float* be3 = (const float*)d_in[13];
  const float* Wp  = (const float*)d_in[14];
  const float* bp  = (const float*)d_in[15];
  const float* gp  = (const float*)d_in[16];
  const float* bep = (const float*)d_in[17];
  const float* Wf  = (const float*)d_in[18];
  const float* bf  = (const float*)d_in[19];

  float*  pooled = (float*)d_ws;                                   // 128 KB
  ushort* W2s = (ushort*)((char*)d_ws + Bb * C3 * sizeof(float));  // 16 KB
  ushort* W3s = W2s + 8192;                                        // 64 KB

  hipMemsetAsync(pooled, 0, Bb * C3 * sizeof(float), stream);
  prepW<<<160, 256, 0, stream>>>(W2, W3, W2s, W3s);
  stageA<<<Bb * BLK_PER_BATCH, 512, 0, stream>>>(
      pc, W1, b1, g1, be1, W2s, b2, g2, be2, W3s, b3, g3, be3, pooled);
  stageB<<<Bb * 4, 256, 0, stream>>>(pooled, img, Wp, bp, gp, bep, Wf, bf,
                                     (float*)d_out);
}

// Round 12
// 313.124 us; speedup vs baseline: 1.4865x; 1.1501x over previous
//
#include <hip/hip_runtime.h>

#define EPS 1e-5f

constexpr int Bb  = 128;     // batches
constexpr int Np  = 8192;    // points per batch
constexpr int C1  = 64, C2 = 128, C3 = 256;
constexpr int WAVES = 8;     // 512 threads
constexpr int P   = 128;     // points per chunk = 8 waves x 16 rows
constexpr int CHUNKS = 8;
constexpr int PTS_PER_BLOCK = P * CHUNKS;          // 1024
constexpr int BLK_PER_BATCH = Np / PTS_PER_BLOCK;  // 8

typedef __attribute__((ext_vector_type(8))) short short8v;  // 8 bf16 = 4 VGPR
typedef __attribute__((ext_vector_type(4))) float f32x4;    // MFMA acc

__device__ __forceinline__ ushort f2bf(float f) {
  uint x = __float_as_uint(f);
  return (ushort)((x + 0x7fffu + ((x >> 16) & 1u)) >> 16);   // RNE
}
__device__ __forceinline__ float bf2f(ushort u) {
  return __uint_as_float((uint)u << 16);
}
__device__ __forceinline__ uint cvt_pk_bf16(float lo, float hi) {
  uint r;
  asm("v_cvt_pk_bf16_f32 %0, %1, %2" : "=v"(r) : "v"(lo), "v"(hi));
  return r;
}

// ---------------------------------------------------------------------------
// prepW: pack W2 [64][128], W3 [128][256] into bf16 B-fragments PLUS one
// column-sum tile per layer (tile 8 for W2, tile 16 for W3): col 0 of the
// sum tile holds sumn Wbf[k][n] (bf16 of f32 sum of bf16 weights), other
// cols zero.  One MFMA against it yields per-row output sums (-> LN mean).
// W2 k-order: identity.  W3 k-order: pair-interleaved (s>>1)+16*(s&1),
// matching h2's uint pair writes — sum tile uses the same permutation.
// ---------------------------------------------------------------------------
__global__ __launch_bounds__(256) void prepW(const float* __restrict__ W2,
                                             const float* __restrict__ W3,
                                             ushort* __restrict__ W2s,
                                             ushort* __restrict__ W3s) {
  const int idx = blockIdx.x * 256 + threadIdx.x;   // 0..44031
  if (idx >= 44032) return;
  if (idx < 9216) {                                 // W2: 9 tiles x 2 kk
    const int i  = idx & 7;
    const int l  = (idx >> 3) & 63;
    const int kk = (idx >> 9) & 1;
    const int t  = idx >> 10;
    const int k  = kk * 32 + (l >> 4) * 8 + i;
    if (t < 8) {
      W2s[idx] = f2bf(W2[k * C2 + t * 16 + (l & 15)]);
    } else {                                        // sum tile
      float s = 0.f;
      if ((l & 15) == 0)
        for (int n = 0; n < C2; ++n) s += bf2f(f2bf(W2[k * C2 + n]));
      W2s[idx] = ((l & 15) == 0) ? f2bf(s) : (ushort)0;
    }
  } else {                                          // W3: 17 tiles x 4 kk
    const int j  = idx - 9216;
    const int i  = j & 7;
    const int l  = (j >> 3) & 63;
    const int kk = (j >> 9) & 3;
    const int nt = j >> 11;
    const int s2 = (l >> 4) * 8 + i;
    const int k  = kk * 32 + (s2 >> 1) + 16 * (s2 & 1);   // pair-interleaved
    if (nt < 16) {
      W3s[j] = f2bf(W3[k * C3 + nt * 16 + (l & 15)]);
    } else {                                        // sum tile
      float s = 0.f;
      if ((l & 15) == 0)
        for (int n = 0; n < C3; ++n) s += bf2f(f2bf(W3[k * C3 + n]));
      W3s[j] = ((l & 15) == 0) ? f2bf(s) : (ushort)0;
    }
  }
}

// ---------------------------------------------------------------------------
// Stage A — r10 skeleton (zero-barrier, 512 thr, 2 waves/SIMD, <=128 VGPR,
// L3 split in two halves w/ bf16 re-pack) + VALU-trim package:
//  * LN means via sum-tile MFMA (no sj accumulation, no sj shfl chains);
//    L1 mean via 4 staging-time pre-reduced scalars (s1 = 3 fma, no shfl).
//  * normalize in fma-form: h = max(fma(fma(y,inv,-mean*inv), g, be), 0).
//  * packed params: W1|b1 as float4/channel; (g,be) interleaved float2.
// s_par (floats): W1pack[64]x4 @0, g1be1 @256, b2 @384, g2be2 @512,
//                 b3 @768, g3be3 @1024.  Total 1536.
// ---------------------------------------------------------------------------
__global__ __launch_bounds__(512) void stageA(
    const float* __restrict__ pc,
    const float* __restrict__ W1, const float* __restrict__ b1,
    const float* __restrict__ g1, const float* __restrict__ be1,
    const ushort* __restrict__ W2s, const float* __restrict__ b2,
    const float* __restrict__ g2, const float* __restrict__ be2,
    const ushort* __restrict__ W3s, const float* __restrict__ b3,
    const float* __restrict__ g3, const float* __restrict__ be3,
    float* __restrict__ pooled)      // [B][C3], pre-zeroed, int-bits atomicMax
{
  __shared__ __align__(16) ushort s_w3[34816];           // 68KB W3 frags+sum
  __shared__ __align__(16) ushort s_w2[9216];            // 18KB W2 frags+sum
  __shared__ __align__(16) ushort s_h1[WAVES * 1024];    // 16KB per-wave 16x64
  __shared__ __align__(16) ushort s_h2[WAVES * 2048];    // 32KB per-wave 16x128
  __shared__ float s_par[1536];                          // 6KB params

  const int tid  = threadIdx.x;          // 0..511
  const int lane = tid & 63;
  const int w    = tid >> 6;
  const int lrow = lane & 15;            // A-row / C-D col index
  const int lgrp = lane >> 4;
  const int b    = blockIdx.x >> 3;      // / BLK_PER_BATCH
  const int base_pt = (blockIdx.x & (BLK_PER_BATCH - 1)) * PTS_PER_BLOCK;

  // ---- one-time staging ----
  for (int i = tid; i < 1536; i += 512) {
    float v;
    if (i < 256)       { const int q = i & 3, c = i >> 2;
                         v = (q < 3) ? W1[q * 64 + c] : b1[c]; }
    else if (i <  384) { const int p = i - 256; v = (p & 1) ? be1[p >> 1] : g1[p >> 1]; }
    else if (i <  512) { v = b2[i - 384]; }
    else if (i <  768) { const int p = i - 512; v = (p & 1) ? be2[p >> 1] : g2[p >> 1]; }
    else if (i < 1024) { v = b3[i - 768]; }
    else               { const int p = i - 1024; v = (p & 1) ? be3[p >> 1] : g3[p >> 1]; }
    s_par[i] = v;
  }
  for (int q = tid; q < 1152; q += 512)
    ((uint4*)s_w2)[q] = ((const uint4*)W2s)[q];
  for (int q = tid; q < 4352; q += 512)
    ((uint4*)s_w3)[q] = ((const uint4*)W3s)[q];
  __syncthreads();   // the ONLY barrier

  // ---- per-wave pre-reduced sums (once per kernel) ----
  float w1s0, w1s1, w1s2, b1s;   // column sums of W1 rows and b1
  {
    const float4 wp = *(const float4*)&s_par[4 * lane];
    w1s0 = wp.x; w1s1 = wp.y; w1s2 = wp.z; b1s = wp.w;
    for (int m = 1; m < 64; m <<= 1) {
      w1s0 += __shfl_xor(w1s0, m, 64); w1s1 += __shfl_xor(w1s1, m, 64);
      w1s2 += __shfl_xor(w1s2, m, 64); b1s  += __shfl_xor(b1s,  m, 64);
    }
  }
  float Sb2, Sb3;                // sum(b2), sum(b3)
  {
    float v2 = s_par[384 + lane] + s_par[384 + 64 + lane];
    float v3 = 0.f;
#pragma unroll
    for (int q = 0; q < 4; ++q) v3 += s_par[768 + lane * 4 + q];
    for (int m = 1; m < 64; m <<= 1) {
      v2 += __shfl_xor(v2, m, 64); v3 += __shfl_xor(v3, m, 64);
    }
    Sb2 = v2; Sb3 = v3;
  }

  char* const h1b = (char*)(s_h1 + w * 1024);   // wave-private 16x64 bf16
  char* const h2b = (char*)(s_h2 + w * 2048);   // wave-private 16x128 bf16
  const int sw1 = (lrow & 7) << 4;

  float runmax[16];
#pragma unroll
  for (int t = 0; t < 16; ++t) runmax[t] = 0.f;

  // ---- prefetch chunk 0's point ----
  const float* xp0 = pc + (size_t)(b * Np + base_pt + w * 16 + lrow) * 3;
  float x0 = xp0[0], x1 = xp0[1], x2 = xp0[2];

  for (int ch = 0; ch < CHUNKS; ++ch) {
    // ================= layer 1: 3 -> 64, fp32 VALU =================
    float y[16];
#pragma unroll
    for (int j = 0; j < 16; ++j) {
      const float4 wp = *(const float4*)&s_par[4 * (lgrp * 16 + j)];
      y[j] = fmaf(x0, wp.x, fmaf(x1, wp.y, fmaf(x2, wp.z, wp.w)));
    }
    const float s1 = fmaf(x0, w1s0, fmaf(x1, w1s1, fmaf(x2, w1s2, b1s)));
    {  // issue next chunk's pc load now
      const int chn = (ch + 1 < CHUNKS) ? ch + 1 : ch;
      const float* xpn = pc + (size_t)(b * Np + base_pt + chn * P + w * 16 + lrow) * 3;
      x0 = xpn[0]; x1 = xpn[1]; x2 = xpn[2];
    }
    float q1 = 0.f;
#pragma unroll
    for (int j = 0; j < 16; ++j) q1 = fmaf(y[j], y[j], q1);
    q1 += __shfl_xor(q1, 16, 64);
    q1 += __shfl_xor(q1, 32, 64);
    const float m1 = s1 * (1.f / 64.f);
    const float i1 = rsqrtf(q1 * (1.f / 64.f) - m1 * m1 + EPS);
    const float M1 = -m1 * i1;
    {
      uint pk[8];
#pragma unroll
      for (int j2 = 0; j2 < 8; ++j2) {
        const float4 gb = *(const float4*)&s_par[256 + 2 * (lgrp * 16 + 2 * j2)];
        const float z0 = fmaf(y[2 * j2],     i1, M1);
        const float z1 = fmaf(y[2 * j2 + 1], i1, M1);
        const float h0 = fmaxf(fmaf(z0, gb.x, gb.y), 0.f);
        const float h1 = fmaxf(fmaf(z1, gb.z, gb.w), 0.f);
        pk[j2] = cvt_pk_bf16(h0, h1);
      }
      const int base = lrow * 128 + lgrp * 32;   // bytes
      *(uint4*)(h1b + ((base     ) ^ sw1)) = make_uint4(pk[0], pk[1], pk[2], pk[3]);
      *(uint4*)(h1b + ((base + 16) ^ sw1)) = make_uint4(pk[4], pk[5], pk[6], pk[7]);
    }
    // wave-private region: compiler lgkmcnt orders write->read; no barrier.

    // ================= layer 2: 64 -> 128, MFMA (in-wave) =================
    short8v a2[2];
#pragma unroll
    for (int kk = 0; kk < 2; ++kk)
      a2[kk] = *(const short8v*)(h1b + ((lrow * 128 + (kk * 64 + lgrp * 16)) ^ sw1));
    {
      // mean via sum-tile MFMA (tile 8)
      f32x4 accM = (f32x4){Sb2, Sb2, Sb2, Sb2};
#pragma unroll
      for (int kk = 0; kk < 2; ++kk) {
        const short8v wsf = *(const short8v*)((const char*)s_w2 + (((8 * 2 + kk) << 6) + lane) * 16);
        accM = __builtin_amdgcn_mfma_f32_16x16x32_bf16(a2[kk], wsf, accM, 0, 0, 0);
      }
      f32x4 acc2[8];
      float q2[4] = {0.f, 0.f, 0.f, 0.f};
#pragma unroll
      for (int t = 0; t < 8; ++t) {
        const float bb = s_par[384 + t * 16 + lrow];
        acc2[t] = (f32x4){bb, bb, bb, bb};         // bias as C-init
#pragma unroll
        for (int kk = 0; kk < 2; ++kk) {
          const short8v w2f = *(const short8v*)((const char*)s_w2 + (((t * 2 + kk) << 6) + lane) * 16);
          acc2[t] = __builtin_amdgcn_mfma_f32_16x16x32_bf16(a2[kk], w2f, acc2[t], 0, 0, 0);
        }
#pragma unroll
        for (int j = 0; j < 4; ++j) q2[j] = fmaf(acc2[t][j], acc2[t][j], q2[j]);
      }
#pragma unroll
      for (int m = 1; m < 16; m <<= 1)
#pragma unroll
        for (int j = 0; j < 4; ++j) q2[j] += __shfl_xor(q2[j], m, 64);
      float i2[4], M2[4];
#pragma unroll
      for (int j = 0; j < 4; ++j) {
        const float mu = __shfl(accM[j], lane & 48, 64) * (1.f / 128.f);
        i2[j] = rsqrtf(q2[j] * (1.f / 128.f) - mu * mu + EPS);
        M2[j] = -mu * i2[j];
      }
#pragma unroll
      for (int t2 = 0; t2 < 4; ++t2) {
        const int ca = t2 * 32 + lrow, cb = ca + 16;
        const float2 gba = *(const float2*)&s_par[512 + 2 * ca];
        const float2 gbb = *(const float2*)&s_par[512 + 2 * cb];
#pragma unroll
        for (int j = 0; j < 4; ++j) {
          const float za = fmaf(acc2[2 * t2    ][j], i2[j], M2[j]);
          const float zb = fmaf(acc2[2 * t2 + 1][j], i2[j], M2[j]);
          const float ha = fmaxf(fmaf(za, gba.x, gba.y), 0.f);
          const float hb = fmaxf(fmaf(zb, gbb.x, gbb.y), 0.f);
          const int row = lgrp * 4 + j;
          *(uint*)(h2b + row * 256 + ((t2 * 64 + lrow * 4) ^ ((row & 7) << 4))) = cvt_pk_bf16(ha, hb);
        }
      }
    }

    // ======== layer 3: 128 -> 256, MFMA, two halves, in-wave LN ==========
    short8v a3[4];
#pragma unroll
    for (int kk = 0; kk < 4; ++kk)
      a3[kk] = *(const short8v*)(h2b + (lrow * 256 + ((kk * 64 + lgrp * 16) ^ sw1)));

    // mean via sum-tile MFMA (tile 16)
    f32x4 accM3 = (f32x4){Sb3, Sb3, Sb3, Sb3};
#pragma unroll
    for (int kk = 0; kk < 4; ++kk) {
      const short8v wsf = *(const short8v*)((const char*)s_w3 + ((((16 * 4) + kk) << 6) + lane) * 16);
      accM3 = __builtin_amdgcn_mfma_f32_16x16x32_bf16(a3[kk], wsf, accM3, 0, 0, 0);
    }

    float qj[4] = {0.f, 0.f, 0.f, 0.f};
    uint pA[16];                     // half A re-packed to bf16
    {
      f32x4 accA[8];
#pragma unroll
      for (int t = 0; t < 8; ++t) {
        const float bb = s_par[768 + t * 16 + lrow];
        accA[t] = (f32x4){bb, bb, bb, bb};
#pragma unroll
        for (int kk = 0; kk < 4; ++kk) {
          const short8v w3f = *(const short8v*)((const char*)s_w3 + (((t * 4 + kk) << 6) + lane) * 16);
          accA[t] = __builtin_amdgcn_mfma_f32_16x16x32_bf16(a3[kk], w3f, accA[t], 0, 0, 0);
        }
#pragma unroll
        for (int j = 0; j < 4; ++j) qj[j] = fmaf(accA[t][j], accA[t][j], qj[j]);
      }
#pragma unroll
      for (int t = 0; t < 8; ++t) {
        pA[2 * t]     = cvt_pk_bf16(accA[t][0], accA[t][1]);
        pA[2 * t + 1] = cvt_pk_bf16(accA[t][2], accA[t][3]);
      }
    }
    f32x4 accB[8];
#pragma unroll
    for (int t = 8; t < 16; ++t) {
      const float bb = s_par[768 + t * 16 + lrow];
      accB[t - 8] = (f32x4){bb, bb, bb, bb};
#pragma unroll
      for (int kk = 0; kk < 4; ++kk) {
        const short8v w3f = *(const short8v*)((const char*)s_w3 + (((t * 4 + kk) << 6) + lane) * 16);
        accB[t - 8] = __builtin_amdgcn_mfma_f32_16x16x32_bf16(a3[kk], w3f, accB[t - 8], 0, 0, 0);
      }
#pragma unroll
      for (int j = 0; j < 4; ++j) qj[j] = fmaf(accB[t - 8][j], accB[t - 8][j], qj[j]);
    }
#pragma unroll
    for (int m = 1; m < 16; m <<= 1)
#pragma unroll
      for (int j = 0; j < 4; ++j) qj[j] += __shfl_xor(qj[j], m, 64);
    float i3[4], M3[4];
#pragma unroll
    for (int j = 0; j < 4; ++j) {
      const float mu = __shfl(accM3[j], lane & 48, 64) * (1.f / 256.f);
      i3[j] = rsqrtf(qj[j] * (1.f / 256.f) - mu * mu + EPS);
      M3[j] = -mu * i3[j];
    }
    // normalize half B (exact f32 accs)
#pragma unroll
    for (int t = 8; t < 16; ++t) {
      const float2 gb = *(const float2*)&s_par[1024 + 2 * (t * 16 + lrow)];
      float mx = runmax[t];
#pragma unroll
      for (int j = 0; j < 4; ++j) {
        const float z = fmaf(accB[t - 8][j], i3[j], M3[j]);
        mx = fmaxf(mx, fmaxf(fmaf(z, gb.x, gb.y), 0.f));
      }
      runmax[t] = mx;
    }
    // normalize half A (bf16-repacked accs)
#pragma unroll
    for (int t = 0; t < 8; ++t) {
      const float2 gb = *(const float2*)&s_par[1024 + 2 * (t * 16 + lrow)];
      const float v0 = __uint_as_float(pA[2 * t]     << 16);
      const float v1 = __uint_as_float(pA[2 * t]     & 0xffff0000u);
      const float v2 = __uint_as_float(pA[2 * t + 1] << 16);
      const float v3 = __uint_as_float(pA[2 * t + 1] & 0xffff0000u);
      float mx = runmax[t];
      mx = fmaxf(mx, fmaxf(fmaf(fmaf(v0, i3[0], M3[0]), gb.x, gb.y), 0.f));
      mx = fmaxf(mx, fmaxf(fmaf(fmaf(v1, i3[1], M3[1]), gb.x, gb.y), 0.f));
      mx = fmaxf(mx, fmaxf(fmaf(fmaf(v2, i3[2], M3[2]), gb.x, gb.y), 0.f));
      mx = fmaxf(mx, fmaxf(fmaf(fmaf(v3, i3[3], M3[3]), gb.x, gb.y), 0.f));
      runmax[t] = mx;
    }
  }

  // ---- col max across the 4 lgrp groups, then global atomic ----
#pragma unroll
  for (int t = 0; t < 16; ++t) {
    float v = runmax[t];
    v = fmaxf(v, __shfl_xor(v, 16, 64));
    v = fmaxf(v, __shfl_xor(v, 32, 64));
    if (lane < 16)
      atomicMax((int*)&pooled[b * C3 + t * 16 + lane], __float_as_int(v));
  }
}

// ---------------------------------------------------------------------------
// Stage B: pooled -> LN(pooled@Wp+bp) -> film = pc@Wf+bf -> out = s*img + b
// 4 blocks per batch (redundant tiny Wp/LN); each does 1/4 of the Wf columns.
// ---------------------------------------------------------------------------
__global__ __launch_bounds__(256) void stageB(
    const float* __restrict__ pooled,  // [B][256]
    const float* __restrict__ img,     // [B][512]
    const float* __restrict__ Wp, const float* __restrict__ bp,
    const float* __restrict__ gp, const float* __restrict__ bep,
    const float* __restrict__ Wf, const float* __restrict__ bf,
    float* __restrict__ out)           // [B][512]
{
  __shared__ float s_pool[C3];
  __shared__ float s_pc[C3];
  __shared__ float s_red[8];
  __shared__ float s_film[256];

  const int t = threadIdx.x;
  const int b = blockIdx.x >> 2;
  const int qq = blockIdx.x & 3;
  const int lane = t & 63, w = t >> 6;

  s_pool[t] = pooled[b * C3 + t];
  __syncthreads();

  float ya = bp[t], yb = 0.f;
  for (int k = 0; k < C3; k += 2) {
    ya += s_pool[k]     * Wp[k * C3 + t];
    yb += s_pool[k + 1] * Wp[(k + 1) * C3 + t];
  }
  const float y = ya + yb;

  float s = y, q = y * y;
  for (int m = 1; m < 64; m <<= 1) { s += __shfl_xor(s, m, 64); q += __shfl_xor(q, m, 64); }
  if (lane == 0) { s_red[w * 2] = s; s_red[w * 2 + 1] = q; }
  __syncthreads();
  s = s_red[0] + s_red[2] + s_red[4] + s_red[6];
  q = s_red[1] + s_red[3] + s_red[5] + s_red[7];
  const float mean = s * (1.f / 256.f);
  const float var  = q * (1.f / 256.f) - mean * mean;
  const float inv  = rsqrtf(var + EPS);
  s_pc[t] = (y - mean) * inv * gp[t] + bep[t];
  __syncthreads();

  // this block's film column: t<128 -> scale col qq*128+t; t>=128 -> bias col
  const int cc = qq * 128 + (t & 127) + ((t >> 7) * 512);
  float fa = bf[cc], fb = 0.f;
  for (int k = 0; k < C3; k += 2) {
    fa += s_pc[k]     * Wf[k * 1024 + cc];
    fb += s_pc[k + 1] * Wf[(k + 1) * 1024 + cc];
  }
  s_film[t] = fa + fb;
  __syncthreads();

  if (t < 128) {
    const int col = qq * 128 + t;
    out[b * 512 + col] = s_film[t] * img[b * 512 + col] + s_film[128 + t];
  }
}

extern "C" void kernel_launch(void* const* d_in, const int* in_sizes, int n_in,
                              void* d_out, int out_size, void* d_ws, size_t ws_size,
                              hipStream_t stream) {
  const float* pc  = (const float*)d_in[0];
  const float* img = (const float*)d_in[1];
  const float* W1  = (const float*)d_in[2];
  const float* b1  = (const float*)d_in[3];
  const float* g1  = (const float*)d_in[4];
  const float* be1 = (const float*)d_in[5];
  const float* W2  = (const float*)d_in[6];
  const float* b2  = (const float*)d_in[7];
  const float* g2  = (const float*)d_in[8];
  const float* be2 = (const float*)d_in[9];
  const float* W3  = (const float*)d_in[10];
  const float* b3  = (const float*)d_in[11];
  const float* g3  = (const float*)d_in[12];
  const float* be3 = (const float*)d_in[13];
  const float* Wp  = (const float*)d_in[14];
  const float* bp  = (const float*)d_in[15];
  const float* gp  = (const float*)d_in[16];
  const float* bep = (const float*)d_in[17];
  const float* Wf  = (const float*)d_in[18];
  const float* bf  = (const float*)d_in[19];

  float*  pooled = (float*)d_ws;                                    // 128 KB
  ushort* W2s = (ushort*)((char*)d_ws + 131072);                    // 18 KB
  ushort* W3s = (ushort*)((char*)d_ws + 131072 + 18432);            // 68 KB

  hipMemsetAsync(pooled, 0, Bb * C3 * sizeof(float), stream);
  prepW<<<172, 256, 0, stream>>>(W2, W3, W2s, W3s);
  stageA<<<Bb * BLK_PER_BATCH, 512, 0, stream>>>(
      pc, W1, b1, g1, be1, W2s, b2, g2, be2, W3s, b3, g3, be3, pooled);
  stageB<<<Bb * 4, 256, 0, stream>>>(pooled, img, Wp, bp, gp, bep, Wf, bf,
                                     (float*)d_out);
}